// Round 1
// baseline (2214.770 us; speedup 1.0000x reference)
//
#include <hip/hip_runtime.h>
#include <hip/hip_bf16.h>
#include <stdint.h>

#define T_TOKENS 8192
#define D_DIM 512
#define F_DIM 2048
#define E_NUM 8

// ---------------------------------------------------------------------------
// helpers: bf16 <-> fp32 bit tricks (unpack 2 bf16 from one uint32)
// ---------------------------------------------------------------------------
__device__ __forceinline__ float bf16lo(uint32_t u) {
    union { uint32_t i; float f; } c; c.i = u << 16; return c.f;
}
__device__ __forceinline__ float bf16hi(uint32_t u) {
    union { uint32_t i; float f; } c; c.i = u & 0xffff0000u; return c.f;
}

// ---------------------------------------------------------------------------
// init: zero prob sums + per-expert counters (d_ws is poisoned each call)
// ---------------------------------------------------------------------------
__global__ void moe_init(float* __restrict__ probs_sum, int* __restrict__ count) {
    int tid = threadIdx.x;
    if (tid < E_NUM) { probs_sum[tid] = 0.f; count[tid] = 0; }
}

// ---------------------------------------------------------------------------
// router: one wave per token. logits = x[t] @ gate_w, softmax, top-2,
// normalized weights, append to per-expert gather lists.
// ---------------------------------------------------------------------------
__global__ __launch_bounds__(256) void moe_router(
    const float* __restrict__ x, const float* __restrict__ gw,
    float* __restrict__ probs_sum, int* __restrict__ count,
    int* __restrict__ tok_list, float* __restrict__ wgt_list)
{
    __shared__ float sgw[D_DIM * E_NUM];   // 16 KB
    int tid = threadIdx.x;
    for (int i = tid; i < D_DIM * E_NUM; i += 256) sgw[i] = gw[i];
    __syncthreads();

    int wave = tid >> 6, lane = tid & 63;
    int t = blockIdx.x * 4 + wave;

    float acc[E_NUM];
#pragma unroll
    for (int e = 0; e < E_NUM; ++e) acc[e] = 0.f;

    const float4* xt = (const float4*)(x + (size_t)t * D_DIM);
#pragma unroll
    for (int i = 0; i < 2; ++i) {
        float4 xv = xt[lane + 64 * i];
        int d0 = (lane + 64 * i) * 4;
        const float* xp = &xv.x;
#pragma unroll
        for (int j = 0; j < 4; ++j) {
            float xj = xp[j];
#pragma unroll
            for (int e = 0; e < E_NUM; ++e) acc[e] += xj * sgw[(d0 + j) * E_NUM + e];
        }
    }
    // wave-64 reduction of 8 partial dot products
#pragma unroll
    for (int off = 32; off > 0; off >>= 1) {
#pragma unroll
        for (int e = 0; e < E_NUM; ++e) acc[e] += __shfl_down(acc[e], off);
    }

    if (lane == 0) {
        float m = acc[0];
#pragma unroll
        for (int e = 1; e < E_NUM; ++e) m = fmaxf(m, acc[e]);
        float p[E_NUM], s = 0.f;
#pragma unroll
        for (int e = 0; e < E_NUM; ++e) { p[e] = __expf(acc[e] - m); s += p[e]; }
        float inv = 1.f / s;
#pragma unroll
        for (int e = 0; e < E_NUM; ++e) { p[e] *= inv; atomicAdd(&probs_sum[e], p[e]); }

        // top-2 (ties -> lower index, matching lax.top_k)
        int e1 = 0;
#pragma unroll
        for (int e = 1; e < E_NUM; ++e) if (p[e] > p[e1]) e1 = e;
        int e2 = (e1 == 0) ? 1 : 0;
#pragma unroll
        for (int e = 0; e < E_NUM; ++e) if (e != e1 && p[e] > p[e2]) e2 = e;

        float wsum = p[e1] + p[e2];
        float wn1 = p[e1] / wsum, wn2 = p[e2] / wsum;

        int pos1 = atomicAdd(&count[e1], 1);
        tok_list[e1 * T_TOKENS + pos1] = t;
        wgt_list[e1 * T_TOKENS + pos1] = wn1;
        int pos2 = atomicAdd(&count[e2], 1);
        tok_list[e2 * T_TOKENS + pos2] = t;
        wgt_list[e2 * T_TOKENS + pos2] = wn2;
    }
}

// ---------------------------------------------------------------------------
// fused per-expert FFN over an 8-token tile.
//   hidden = gelu(x @ w1[e] + b1[e])   (kept in LDS as bf16, [f][t])
//   y[tok] += wgt * (hidden @ w2[e] + b2[e])   via atomicAdd
// ---------------------------------------------------------------------------
__global__ __launch_bounds__(256) void moe_ffn(
    const float* __restrict__ x,
    const float* __restrict__ w1, const float* __restrict__ b1,
    const float* __restrict__ w2, const float* __restrict__ b2,
    const int* __restrict__ count, const int* __restrict__ tok_list,
    const float* __restrict__ wgt_list, float* __restrict__ y)
{
    int e    = blockIdx.x >> 10;
    int tile = blockIdx.x & 1023;
    int cnt  = count[e];
    int start = tile * 8;
    if (start >= cnt) return;

    __shared__ float          xs[D_DIM][8];   // 16 KB, transposed [k][t]
    __shared__ __hip_bfloat16 hs[F_DIM][8];   // 32 KB, transposed [f][t]
    __shared__ int   stok[8];
    __shared__ float swgt[8];

    int tid = threadIdx.x;
    if (tid < 8) {
        int idx = start + tid;
        if (idx < cnt) {
            stok[tid] = tok_list[e * T_TOKENS + idx];
            swgt[tid] = wgt_list[e * T_TOKENS + idx];
        } else {
            stok[tid] = 0;     // compute garbage, weight 0 -> contributes 0
            swgt[tid] = 0.f;
        }
    }
    __syncthreads();

    // stage x tile (transposed into [k][t])
    {
        int r = tid >> 5, c = tid & 31;  // 32 threads per token row
        const float4* xr = (const float4*)(x + (size_t)stok[r] * D_DIM);
#pragma unroll
        for (int i = 0; i < 4; ++i) {
            float4 v = xr[c + 32 * i];
            int d0 = (c + 32 * i) * 4;
            xs[d0 + 0][r] = v.x; xs[d0 + 1][r] = v.y;
            xs[d0 + 2][r] = v.z; xs[d0 + 3][r] = v.w;
        }
    }
    __syncthreads();

    // ---- phase A: hidden = gelu(x @ w1 + b1) -> LDS bf16 -------------------
#pragma unroll 1
    for (int p = 0; p < 2; ++p) {
        int f0 = p * 1024 + tid * 4;          // 4 contiguous f per thread
        float a[8][4];
#pragma unroll
        for (int t = 0; t < 8; ++t)
#pragma unroll
            for (int j = 0; j < 4; ++j) a[t][j] = 0.f;

        const float* w1p = w1 + (size_t)e * D_DIM * F_DIM + f0;
        for (int k = 0; k < D_DIM; ++k) {
            float4 w   = *(const float4*)(w1p + (size_t)k * F_DIM);
            float4 xlo = *(const float4*)&xs[k][0];
            float4 xhi = *(const float4*)&xs[k][4];
            float xv[8] = { xlo.x, xlo.y, xlo.z, xlo.w, xhi.x, xhi.y, xhi.z, xhi.w };
            const float* wp = &w.x;
#pragma unroll
            for (int t = 0; t < 8; ++t)
#pragma unroll
                for (int j = 0; j < 4; ++j)
                    a[t][j] += xv[t] * wp[j];
        }
        float4 b = *(const float4*)(b1 + e * F_DIM + f0);
        const float* bp = &b.x;
#pragma unroll
        for (int j = 0; j < 4; ++j)
#pragma unroll
            for (int t = 0; t < 8; ++t) {
                float h = a[t][j] + bp[j];
                h = 0.5f * h * (1.f + erff(h * 0.70710678118654752440f)); // exact gelu
                hs[f0 + j][t] = __float2bfloat16(h);
            }
    }
    __syncthreads();

    // ---- phase B: out = hidden @ w2 + b2; y += wgt * out -------------------
    int d0 = tid * 2;                         // 2 contiguous d per thread
    float o0[8], o1[8];
#pragma unroll
    for (int t = 0; t < 8; ++t) { o0[t] = 0.f; o1[t] = 0.f; }

    const float* w2p = w2 + (size_t)e * F_DIM * D_DIM + d0;
    for (int f = 0; f < F_DIM; ++f) {
        float2 w = *(const float2*)(w2p + (size_t)f * D_DIM);
        uint4 hv = *(const uint4*)&hs[f][0];  // 8 bf16, broadcast b128
        float xv[8] = {
            bf16lo(hv.x), bf16hi(hv.x), bf16lo(hv.y), bf16hi(hv.y),
            bf16lo(hv.z), bf16hi(hv.z), bf16lo(hv.w), bf16hi(hv.w)
        };
#pragma unroll
        for (int t = 0; t < 8; ++t) { o0[t] += xv[t] * w.x; o1[t] += xv[t] * w.y; }
    }

    float bx = b2[e * D_DIM + d0];
    float by = b2[e * D_DIM + d0 + 1];
#pragma unroll
    for (int t = 0; t < 8; ++t) {
        float wg = swgt[t];
        if (wg != 0.f) {
            float* yp = y + (size_t)stok[t] * D_DIM + d0;
            atomicAdd(yp,     wg * (o0[t] + bx));
            atomicAdd(yp + 1, wg * (o1[t] + by));
        }
    }
}

// ---------------------------------------------------------------------------
// load-balance loss: E * sum_e (mean_e)^2
// ---------------------------------------------------------------------------
__global__ void moe_loss(const float* __restrict__ probs_sum, float* __restrict__ out) {
    if (threadIdx.x == 0) {
        float s = 0.f;
        for (int e = 0; e < E_NUM; ++e) {
            float m = probs_sum[e] / (float)T_TOKENS;
            s += m * m;
        }
        out[0] = (float)E_NUM * s;
    }
}

// ---------------------------------------------------------------------------
extern "C" void kernel_launch(void* const* d_in, const int* in_sizes, int n_in,
                              void* d_out, int out_size, void* d_ws, size_t ws_size,
                              hipStream_t stream) {
    const float* x  = (const float*)d_in[0];
    const float* gw = (const float*)d_in[1];
    const float* w1 = (const float*)d_in[2];
    const float* b1 = (const float*)d_in[3];
    const float* w2 = (const float*)d_in[4];
    const float* b2 = (const float*)d_in[5];
    float* out = (float*)d_out;

    // workspace layout
    float* probs_sum = (float*)d_ws;                                   // 8 f32
    int*   count     = (int*)((char*)d_ws + 64);                       // 8 i32
    int*   tok_list  = (int*)((char*)d_ws + 128);                      // E*T i32
    float* wgt_list  = (float*)((char*)d_ws + 128 + (size_t)E_NUM * T_TOKENS * 4);

    hipMemsetAsync(d_out, 0, (size_t)out_size * sizeof(float), stream);
    moe_init<<<1, 64, 0, stream>>>(probs_sum, count);
    moe_router<<<T_TOKENS / 4, 256, 0, stream>>>(x, gw, probs_sum, count, tok_list, wgt_list);
    moe_ffn<<<E_NUM * 1024, 256, 0, stream>>>(x, w1, b1, w2, b2, count, tok_list, wgt_list, out);
    moe_loss<<<1, 64, 0, stream>>>(probs_sum, out + (size_t)T_TOKENS * D_DIM);
}

// Round 2
// 422.837 us; speedup vs baseline: 5.2379x; 5.2379x over previous
//
#include <hip/hip_runtime.h>
#include <stdint.h>

#define T_TOKENS 8192
#define D_DIM 512
#define F_DIM 2048
#define E_NUM 8

typedef short short8 __attribute__((ext_vector_type(8)));
typedef float f32x4 __attribute__((ext_vector_type(4)));

// ---------------- bf16 helpers (RNE, finite inputs) -------------------------
__device__ __forceinline__ unsigned short f2bf(float f) {
    union { float f; unsigned int u; } c; c.f = f;
    unsigned int u = c.u;
    unsigned int r = (u + 0x7fffu + ((u >> 16) & 1u)) >> 16;
    return (unsigned short)r;
}
__device__ __forceinline__ unsigned int pack2(float a, float b) {
    return (unsigned int)f2bf(a) | ((unsigned int)f2bf(b) << 16);
}

// ws layout (bytes)
#define WS_COUNT 0
#define WS_PART  1024
#define WS_TOK   16384
#define WS_WGT   (WS_TOK + E_NUM * T_TOKENS * 4)
#define WS_W1B   (1u << 20)
#define WS_W2B   (WS_W1B + 16777216u)

// ---------------------------------------------------------------------------
__global__ void moe_init(int* __restrict__ count) {
    if (threadIdx.x < E_NUM) count[threadIdx.x] = 0;
}

// ---------------------------------------------------------------------------
// Convert w1/w2 fp32 -> bf16 in MFMA B-fragment order.
// w1 frag linear idx: (((e*128 + ft)*16 + ks)*64 + L)*8 + j
//   element = w1[e][ks*32 + (L>>4)*8 + j][ft*16 + (L&15)]
// w2 frag linear idx: (((e*32 + dt)*64 + fs)*64 + L)*8 + j
//   element = w2[e][fs*32 + (L>>4)*8 + j][dt*16 + (L&15)]
// ---------------------------------------------------------------------------
__global__ __launch_bounds__(256) void moe_convert(
    const float* __restrict__ w1, const float* __restrict__ w2,
    unsigned short* __restrict__ w1b, unsigned short* __restrict__ w2b)
{
    int gid = blockIdx.x * 256 + threadIdx.x;   // 0 .. 2*1048576-1
    bool is2 = gid >= 1048576;
    int o = is2 ? gid - 1048576 : gid;
    int L = o & 63, q = L >> 4, n = L & 15;
    const float* base;
    int stride;
    if (!is2) {
        int ks = (o >> 6) & 15, ft = (o >> 10) & 127, e = o >> 17;
        base = w1 + ((size_t)e << 20) + (size_t)(ks * 32 + q * 8) * 2048 + ft * 16 + n;
        stride = 2048;
    } else {
        int fs = (o >> 6) & 63, dt = (o >> 12) & 31, e = o >> 17;
        base = w2 + ((size_t)e << 20) + (size_t)(fs * 32 + q * 8) * 512 + dt * 16 + n;
        stride = 512;
    }
    float v[8];
#pragma unroll
    for (int j = 0; j < 8; ++j) v[j] = base[(size_t)j * stride];
    uint4 pk;
    pk.x = pack2(v[0], v[1]); pk.y = pack2(v[2], v[3]);
    pk.z = pack2(v[4], v[5]); pk.w = pack2(v[6], v[7]);
    unsigned short* dst = (is2 ? w2b : w1b) + (size_t)o * 8;
    *(uint4*)dst = pk;
}

// ---------------------------------------------------------------------------
// Router: 256 threads = 4 waves; wave handles 8 tokens with lane=(token,expert).
// Per-block LDS lists; ONE reservation atomic per expert per block.
// ---------------------------------------------------------------------------
__global__ __launch_bounds__(256) void moe_router(
    const float* __restrict__ x, const float* __restrict__ gw,
    int* __restrict__ count, int* __restrict__ tok_list,
    float* __restrict__ wgt_list, float* __restrict__ part)
{
    __shared__ float pprob[E_NUM];
    __shared__ int   lcnt[E_NUM];
    __shared__ int   gbase[E_NUM];
    __shared__ int   ltok[E_NUM][32];
    __shared__ float lwgt[E_NUM][32];

    int tid = threadIdx.x;
    if (tid < E_NUM) { pprob[tid] = 0.f; lcnt[tid] = 0; }
    __syncthreads();

    int lane = tid & 63, wv = tid >> 6;
    int ts = lane >> 3, e = lane & 7;
    int t = blockIdx.x * 32 + wv * 8 + ts;

    const float* xt = x + (size_t)t * D_DIM;
    float acc = 0.f;
#pragma unroll 8
    for (int d = 0; d < D_DIM; d += 4) {
        float4 xv = *(const float4*)(xt + d);
        acc += xv.x * gw[(d + 0) * E_NUM + e] + xv.y * gw[(d + 1) * E_NUM + e]
             + xv.z * gw[(d + 2) * E_NUM + e] + xv.w * gw[(d + 3) * E_NUM + e];
    }
    // softmax over 8-lane expert group
    float m = acc;
#pragma unroll
    for (int off = 1; off < 8; off <<= 1) m = fmaxf(m, __shfl_xor(m, off));
    float ex = __expf(acc - m);
    float s = ex;
#pragma unroll
    for (int off = 1; off < 8; off <<= 1) s += __shfl_xor(s, off);
    float p = ex / s;
    atomicAdd(&pprob[e], p);

    // top-1 (ties -> lower index)
    float v = p; int i = e;
#pragma unroll
    for (int off = 4; off; off >>= 1) {
        float ov = __shfl_xor(v, off); int oi = __shfl_xor(i, off);
        if (ov > v || (ov == v && oi < i)) { v = ov; i = oi; }
    }
    int e1 = i; float p1 = v;
    // top-2
    float v2 = (e == e1) ? -1.f : p; int i2 = e;
#pragma unroll
    for (int off = 4; off; off >>= 1) {
        float ov = __shfl_xor(v2, off); int oi = __shfl_xor(i2, off);
        if (ov > v2 || (ov == v2 && oi < i2)) { v2 = ov; i2 = oi; }
    }
    int e2 = i2; float p2 = v2;

    if (e == 0) {
        float inv = 1.f / (p1 + p2);
        int s1 = atomicAdd(&lcnt[e1], 1); ltok[e1][s1] = t; lwgt[e1][s1] = p1 * inv;
        int s2 = atomicAdd(&lcnt[e2], 1); ltok[e2][s2] = t; lwgt[e2][s2] = p2 * inv;
    }
    __syncthreads();
    if (tid < E_NUM) {
        gbase[tid] = atomicAdd(&count[tid], lcnt[tid]);
        part[blockIdx.x * E_NUM + tid] = pprob[tid];
    }
    __syncthreads();
    int ee = tid >> 5, ss = tid & 31;
    if (ss < lcnt[ee]) {
        int dst = ee * T_TOKENS + gbase[ee] + ss;
        tok_list[dst] = ltok[ee][ss];
        wgt_list[dst] = lwgt[ee][ss];
    }
}

// ---------------------------------------------------------------------------
// FFN: block = (expert, 64-token tile), 512 threads = 8 waves.
// Phase A: hidden = gelu(X @ W1 + b1) per 256-f chunk -> LDS bf16
// Phase B: out += hidden_chunk @ W2 ; final: y += wgt*(out + b2) via atomics.
// ---------------------------------------------------------------------------
__global__ __launch_bounds__(512, 2) void moe_ffn(
    const float* __restrict__ x,
    const unsigned short* __restrict__ w1b, const float* __restrict__ b1,
    const unsigned short* __restrict__ w2b, const float* __restrict__ b2,
    const int* __restrict__ count, const int* __restrict__ tok_list,
    const float* __restrict__ wgt_list, float* __restrict__ y)
{
    int e = blockIdx.x & 7;          // expert -> XCD affinity (bx % 8)
    int tile = blockIdx.x >> 3;
    int cnt = count[e];
    if (tile * 64 >= cnt) return;

    __shared__ __align__(16) unsigned short Xf[64 * 64 * 8];   // 64 KB, A-frag order
    __shared__ __align__(16) unsigned short hs[64][264];       // 33.8 KB, padded
    __shared__ int   stok[64];
    __shared__ float swgt[64];

    int tid = threadIdx.x;
    if (tid < 64) {
        int s = tile * 64 + tid;
        if (s < cnt) { stok[tid] = tok_list[e * T_TOKENS + s]; swgt[tid] = wgt_list[e * T_TOKENS + s]; }
        else         { stok[tid] = 0; swgt[tid] = 0.f; }
    }
    __syncthreads();

    // ---- stage X tile into LDS in A-fragment order -------------------------
    {
        int tl = tid >> 3;                 // token slot 0..63
        int kb = (tid & 7) * 64;           // 64 k per thread
        const float* xr = x + (size_t)stok[tl] * D_DIM + kb;
        int mt = tl >> 4, n = tl & 15;
#pragma unroll
        for (int g = 0; g < 8; ++g) {
            float4 v0 = *(const float4*)(xr + g * 8);
            float4 v1 = *(const float4*)(xr + g * 8 + 4);
            int ka = kb + g * 8;
            int ks = ka >> 5, q = (ka >> 3) & 3;
            uint4 pk;
            pk.x = pack2(v0.x, v0.y); pk.y = pack2(v0.z, v0.w);
            pk.z = pack2(v1.x, v1.y); pk.w = pack2(v1.z, v1.w);
            *(uint4*)&Xf[(size_t)((mt * 16 + ks) * 64 + q * 16 + n) * 8] = pk;
        }
    }
    __syncthreads();

    int wv = tid >> 6, lane = tid & 63;
    int q = lane >> 4, n = lane & 15;

    f32x4 aB[4][4];   // [nt][mt] output accumulators (persist across chunks)
#pragma unroll
    for (int a = 0; a < 4; ++a)
#pragma unroll
        for (int b = 0; b < 4; ++b) aB[a][b] = (f32x4){0.f, 0.f, 0.f, 0.f};

#pragma unroll 1
    for (int c = 0; c < 8; ++c) {
        // ---- phase A: 2 f-tiles per wave, K=512 ----------------------------
        f32x4 aA[2][4];
#pragma unroll
        for (int a = 0; a < 2; ++a)
#pragma unroll
            for (int b = 0; b < 4; ++b) aA[a][b] = (f32x4){0.f, 0.f, 0.f, 0.f};

        int ft0 = c * 16 + wv * 2;
        const unsigned short* bp0 = w1b + ((size_t)((e * 128 + ft0) * 16) * 64 + lane) * 8;
        const unsigned short* bp1 = bp0 + 16 * 64 * 8;
#pragma unroll 2
        for (int ks = 0; ks < 16; ++ks) {
            short8 bf0 = *(const short8*)(bp0 + ks * 512);
            short8 bf1 = *(const short8*)(bp1 + ks * 512);
#pragma unroll
            for (int mt = 0; mt < 4; ++mt) {
                short8 a = *(const short8*)&Xf[(size_t)((mt * 16 + ks) * 64 + lane) * 8];
                aA[0][mt] = __builtin_amdgcn_mfma_f32_16x16x32_bf16(a, bf0, aA[0][mt], 0, 0, 0);
                aA[1][mt] = __builtin_amdgcn_mfma_f32_16x16x32_bf16(a, bf1, aA[1][mt], 0, 0, 0);
            }
        }
        __syncthreads();   // phase B of previous chunk done reading hs
        // ---- epilogue: bias + gelu -> hs -----------------------------------
#pragma unroll
        for (int nt = 0; nt < 2; ++nt) {
            int fg = (ft0 + nt) * 16 + n;
            float bb = b1[e * F_DIM + fg];
            int fl = (wv * 2 + nt) * 16 + n;
#pragma unroll
            for (int mt = 0; mt < 4; ++mt)
#pragma unroll
                for (int r = 0; r < 4; ++r) {
                    float h = aA[nt][mt][r] + bb;
                    h = 0.5f * h * (1.f + erff(h * 0.70710678118654752440f));
                    hs[mt * 16 + q * 4 + r][fl] = f2bf(h);
                }
        }
        __syncthreads();
        // ---- phase B: 4 d-tiles per wave, K=256 (this chunk) ---------------
#pragma unroll 2
        for (int ks2 = 0; ks2 < 8; ++ks2) {
            int fs = c * 8 + ks2;
            short8 a[4];
#pragma unroll
            for (int mt = 0; mt < 4; ++mt)
                a[mt] = *(const short8*)&hs[mt * 16 + n][ks2 * 32 + q * 8];
#pragma unroll
            for (int nt = 0; nt < 4; ++nt) {
                int dt = wv * 4 + nt;
                short8 bb = *(const short8*)(w2b + ((size_t)((e * 32 + dt) * 64 + fs) * 64 + lane) * 8);
#pragma unroll
                for (int mt = 0; mt < 4; ++mt)
                    aB[nt][mt] = __builtin_amdgcn_mfma_f32_16x16x32_bf16(a[mt], bb, aB[nt][mt], 0, 0, 0);
            }
        }
    }

    // ---- final epilogue: y += wgt * (out + b2) ----------------------------
#pragma unroll
    for (int nt = 0; nt < 4; ++nt) {
        int d = wv * 64 + nt * 16 + n;
        float bb = b2[e * D_DIM + d];
#pragma unroll
        for (int mt = 0; mt < 4; ++mt)
#pragma unroll
            for (int r = 0; r < 4; ++r) {
                int m = mt * 16 + q * 4 + r;
                float wg = swgt[m];
                if (wg != 0.f)
                    atomicAdd(y + (size_t)stok[m] * D_DIM + d, wg * (aB[nt][mt][r] + bb));
            }
    }
}

// ---------------------------------------------------------------------------
__global__ void moe_loss(const float* __restrict__ part, float* __restrict__ out) {
    __shared__ float pl[E_NUM];
    int tid = threadIdx.x;
    if (tid < E_NUM) pl[tid] = 0.f;
    __syncthreads();
    float s = 0.f;
    for (int i = tid; i < 256 * E_NUM; i += 256) s += part[i];   // i&7 constant per thread
    atomicAdd(&pl[tid & 7], s);
    __syncthreads();
    if (tid == 0) {
        float acc = 0.f;
        for (int e = 0; e < E_NUM; ++e) {
            float m = pl[e] / (float)T_TOKENS;
            acc += m * m;
        }
        out[0] = (float)E_NUM * acc;
    }
}

// ---------------------------------------------------------------------------
extern "C" void kernel_launch(void* const* d_in, const int* in_sizes, int n_in,
                              void* d_out, int out_size, void* d_ws, size_t ws_size,
                              hipStream_t stream) {
    const float* x  = (const float*)d_in[0];
    const float* gw = (const float*)d_in[1];
    const float* w1 = (const float*)d_in[2];
    const float* b1 = (const float*)d_in[3];
    const float* w2 = (const float*)d_in[4];
    const float* b2 = (const float*)d_in[5];
    float* out = (float*)d_out;

    char* ws = (char*)d_ws;
    int*   count     = (int*)(ws + WS_COUNT);
    float* part      = (float*)(ws + WS_PART);
    int*   tok_list  = (int*)(ws + WS_TOK);
    float* wgt_list  = (float*)(ws + WS_WGT);
    unsigned short* w1b = (unsigned short*)(ws + WS_W1B);
    unsigned short* w2b = (unsigned short*)(ws + WS_W2B);

    hipMemsetAsync(d_out, 0, (size_t)out_size * sizeof(float), stream);
    moe_init<<<1, 64, 0, stream>>>(count);
    moe_convert<<<8192, 256, 0, stream>>>(w1, w2, w1b, w2b);
    moe_router<<<T_TOKENS / 32, 256, 0, stream>>>(x, gw, count, tok_list, wgt_list, part);
    moe_ffn<<<E_NUM * 128, 512, 0, stream>>>(x, w1b, b1, w2b, b2, count, tok_list, wgt_list, out);
    moe_loss<<<1, 256, 0, stream>>>(part, out + (size_t)T_TOKENS * D_DIM);
}

// Round 3
// 359.068 us; speedup vs baseline: 6.1681x; 1.1776x over previous
//
#include <hip/hip_runtime.h>
#include <stdint.h>

#define T_TOKENS 8192
#define D_DIM 512
#define F_DIM 2048
#define E_NUM 8

typedef short short8 __attribute__((ext_vector_type(8)));
typedef float f32x4 __attribute__((ext_vector_type(4)));

// ---------------- bf16 helpers (RNE, finite inputs) -------------------------
__device__ __forceinline__ unsigned short f2bf(float f) {
    union { float f; unsigned int u; } c; c.f = f;
    unsigned int u = c.u;
    unsigned int r = (u + 0x7fffu + ((u >> 16) & 1u)) >> 16;
    return (unsigned short)r;
}
__device__ __forceinline__ unsigned int pack2(float a, float b) {
    return (unsigned int)f2bf(a) | ((unsigned int)f2bf(b) << 16);
}

// ws layout (bytes)
#define WS_COUNT 0
#define WS_PART  1024
#define WS_TOK   16384
#define WS_WGT   (WS_TOK + E_NUM * T_TOKENS * 4)
#define WS_W1B   (1u << 20)
#define WS_W2B   (WS_W1B + 16777216u)

// ---------------------------------------------------------------------------
__global__ void moe_init(int* __restrict__ count) {
    if (threadIdx.x < E_NUM) count[threadIdx.x] = 0;
}

// ---------------------------------------------------------------------------
// Convert w1/w2 fp32 -> bf16 in MFMA B-fragment order (same layout as R2):
//   frag-lane linear = ((e*(N/16) + ft)*(K/32) + ks)*64 + L
//   element = M[ks*32 + (L>>4)*8 + j][ft*16 + (L&15)]
// LDS-tiled: coalesced float4 reads, coalesced uint4 writes.
// Grid: 4096 blocks for w1 (K=512,N=2048), 4096 for w2 (K=2048,N=512).
// ---------------------------------------------------------------------------
__global__ __launch_bounds__(256) void moe_convert(
    const float* __restrict__ w1, const float* __restrict__ w2,
    unsigned short* __restrict__ w1b, unsigned short* __restrict__ w2b)
{
    __shared__ float ts[32][65];   // 32 k-rows x 64 n-cols (+pad)
    int b = blockIdx.x;
    bool is2 = b >= 4096;
    int o = is2 ? b - 4096 : b;
    int e = o >> 9, r = o & 511;
    int N  = is2 ? 512 : 2048;
    int Ks = is2 ? 64 : 16;
    int ng, ks;
    if (!is2) { ng = r & 31; ks = r >> 5; }
    else      { ng = r & 7;  ks = r >> 3; }

    const float* src = (is2 ? w2 : w1) + ((size_t)e << 20) + (size_t)(ks * 32) * N + ng * 64;
    int tid = threadIdx.x;
    int row = tid >> 3, c4 = (tid & 7) * 4;
    float4 v0 = *(const float4*)(src + (size_t)row * N + c4);
    float4 v1 = *(const float4*)(src + (size_t)row * N + c4 + 32);
    *(float4*)&ts[row][c4] = v0;
    *(float4*)&ts[row][c4 + 32] = v1;
    __syncthreads();

    int f = tid >> 6, L = tid & 63, q = L >> 4, n = L & 15;
    float v[8];
#pragma unroll
    for (int j = 0; j < 8; ++j) v[j] = ts[q * 8 + j][f * 16 + n];
    uint4 pk;
    pk.x = pack2(v[0], v[1]); pk.y = pack2(v[2], v[3]);
    pk.z = pack2(v[4], v[5]); pk.w = pack2(v[6], v[7]);
    size_t fraglane = ((size_t)((e * (N / 16) + ng * 4 + f) * Ks + ks)) * 64 + L;
    unsigned short* dst = (is2 ? w2b : w1b) + fraglane * 8;
    *(uint4*)dst = pk;
}

// ---------------------------------------------------------------------------
// Router: 256 threads = 4 waves; one WAVE per token (8 tokens/wave, looped).
// gate_w held in 64 VGPRs per lane (lane owns d-slice lane*8..lane*8+7).
// Coalesced 1x fetch of x; butterfly reduce; per-block lists, 8 global atomics.
// ---------------------------------------------------------------------------
__global__ __launch_bounds__(256) void moe_router(
    const float* __restrict__ x, const float* __restrict__ gw,
    int* __restrict__ count, int* __restrict__ tok_list,
    float* __restrict__ wgt_list, float* __restrict__ part)
{
    __shared__ float pprob[E_NUM];
    __shared__ int   lcnt[E_NUM];
    __shared__ int   gbase[E_NUM];
    __shared__ int   ltok[E_NUM][64];
    __shared__ float lwgt[E_NUM][64];

    int tid = threadIdx.x;
    if (tid < E_NUM) { pprob[tid] = 0.f; lcnt[tid] = 0; }
    __syncthreads();

    int wv = tid >> 6, lane = tid & 63;

    // gate weights for this lane's d-slice: gw[(lane*8+j)*8 + e] = linear lane*64 + j*8 + e
    float gr[64];
    {
        const float4* gp = (const float4*)(gw + lane * 64);
#pragma unroll
        for (int i = 0; i < 16; ++i) *(float4*)&gr[i * 4] = gp[i];
    }

    float wps[E_NUM];
#pragma unroll
    for (int e = 0; e < E_NUM; ++e) wps[e] = 0.f;

#pragma unroll 1
    for (int i = 0; i < 8; ++i) {
        int t = blockIdx.x * 32 + wv * 8 + i;
        const float4* xp = (const float4*)(x + (size_t)t * D_DIM + lane * 8);
        float4 x0 = xp[0], x1 = xp[1];
        float xv[8] = { x0.x, x0.y, x0.z, x0.w, x1.x, x1.y, x1.z, x1.w };
        float acc[E_NUM];
#pragma unroll
        for (int e = 0; e < E_NUM; ++e) acc[e] = 0.f;
#pragma unroll
        for (int j = 0; j < 8; ++j)
#pragma unroll
            for (int e = 0; e < E_NUM; ++e) acc[e] += xv[j] * gr[j * 8 + e];
        // butterfly over 64 lanes
#pragma unroll
        for (int off = 1; off < 64; off <<= 1)
#pragma unroll
            for (int e = 0; e < E_NUM; ++e) acc[e] += __shfl_xor(acc[e], off);

        float m = acc[0];
#pragma unroll
        for (int e = 1; e < E_NUM; ++e) m = fmaxf(m, acc[e]);
        float p[E_NUM], s = 0.f;
#pragma unroll
        for (int e = 0; e < E_NUM; ++e) { p[e] = __expf(acc[e] - m); s += p[e]; }
        float inv = 1.f / s;
#pragma unroll
        for (int e = 0; e < E_NUM; ++e) { p[e] *= inv; wps[e] += p[e]; }

        // top-2 (ties -> lower index)
        int e1 = 0;
#pragma unroll
        for (int e = 1; e < E_NUM; ++e) if (p[e] > p[e1]) e1 = e;
        int e2 = (e1 == 0) ? 1 : 0;
#pragma unroll
        for (int e = 0; e < E_NUM; ++e) if (e != e1 && p[e] > p[e2]) e2 = e;

        if (lane == 0) {
            float invw = 1.f / (p[e1] + p[e2]);
            int s1 = atomicAdd(&lcnt[e1], 1); ltok[e1][s1] = t; lwgt[e1][s1] = p[e1] * invw;
            int s2 = atomicAdd(&lcnt[e2], 1); ltok[e2][s2] = t; lwgt[e2][s2] = p[e2] * invw;
        }
    }
    if (lane == 0) {
#pragma unroll
        for (int e = 0; e < E_NUM; ++e) atomicAdd(&pprob[e], wps[e]);
    }
    __syncthreads();
    if (tid < E_NUM) {
        gbase[tid] = atomicAdd(&count[tid], lcnt[tid]);
        part[blockIdx.x * E_NUM + tid] = pprob[tid];
    }
    __syncthreads();
    int ee = tid >> 5;
    for (int ss = tid & 31; ss < lcnt[ee]; ss += 32) {
        int dst = ee * T_TOKENS + gbase[ee] + ss;
        tok_list[dst] = ltok[ee][ss];
        wgt_list[dst] = lwgt[ee][ss];
    }
}

// ---------------------------------------------------------------------------
// FFN item = (expert, 64-token tile, f-half). 512 threads = 8 waves.
// Per f-half: 4 chunks of 256 f. Pipeline:
//   A(c0);  for cc: [barrier; write hs(c); barrier; merged A(c+1)+B(c) | B(c3)]
// Merged loop: 16 iters x (2 w1-loads + 2 w2-loads + LDS reads + 16 MFMAs)
// with 1-deep register prefetch of all 4 weight fragments.
// ---------------------------------------------------------------------------
__global__ __launch_bounds__(512, 2) void moe_ffn(
    const float* __restrict__ x,
    const unsigned short* __restrict__ w1b, const float* __restrict__ b1,
    const unsigned short* __restrict__ w2b, const float* __restrict__ b2,
    const int* __restrict__ count, const int* __restrict__ tok_list,
    const float* __restrict__ wgt_list, float* __restrict__ y)
{
    int e    = blockIdx.x & 7;            // expert -> XCD affinity
    int half = (blockIdx.x >> 3) & 1;     // f-half
    int tile = blockIdx.x >> 4;
    int cnt = count[e];
    if (tile * 64 >= cnt) return;

    __shared__ __align__(16) unsigned short Xf[64 * 64 * 8];   // 64 KB, A-frag order
    __shared__ __align__(16) unsigned short hs[64][264];       // 33.8 KB, padded
    __shared__ int   stok[64];
    __shared__ float swgt[64];

    int tid = threadIdx.x;
    if (tid < 64) {
        int s = tile * 64 + tid;
        if (s < cnt) { stok[tid] = tok_list[e * T_TOKENS + s]; swgt[tid] = wgt_list[e * T_TOKENS + s]; }
        else         { stok[tid] = 0; swgt[tid] = 0.f; }
    }
    __syncthreads();

    // ---- stage X tile into LDS in A-fragment order -------------------------
    {
        int tl = tid >> 3;
        int kb = (tid & 7) * 64;
        const float* xr = x + (size_t)stok[tl] * D_DIM + kb;
        int mt = tl >> 4, nn = tl & 15;
#pragma unroll
        for (int g = 0; g < 8; ++g) {
            float4 v0 = *(const float4*)(xr + g * 8);
            float4 v1 = *(const float4*)(xr + g * 8 + 4);
            int ka = kb + g * 8;
            int ks = ka >> 5, qq = (ka >> 3) & 3;
            uint4 pk;
            pk.x = pack2(v0.x, v0.y); pk.y = pack2(v0.z, v0.w);
            pk.z = pack2(v1.x, v1.y); pk.w = pack2(v1.z, v1.w);
            *(uint4*)&Xf[(size_t)((mt * 16 + ks) * 64 + qq * 16 + nn) * 8] = pk;
        }
    }
    __syncthreads();

    int wv = tid >> 6, lane = tid & 63;
    int q = lane >> 4, n = lane & 15;
    const short8* w1p = (const short8*)w1b;
    const short8* w2p = (const short8*)w2b;

    int c0 = half * 4;

    f32x4 aA[2][4];
    f32x4 aB[4][4];
#pragma unroll
    for (int a = 0; a < 4; ++a)
#pragma unroll
        for (int b = 0; b < 4; ++b) aB[a][b] = (f32x4){0.f, 0.f, 0.f, 0.f};

    // ---- prologue: A(c0) ---------------------------------------------------
    {
#pragma unroll
        for (int a = 0; a < 2; ++a)
#pragma unroll
            for (int b = 0; b < 4; ++b) aA[a][b] = (f32x4){0.f, 0.f, 0.f, 0.f};
        size_t w1L = ((size_t)((e * 128 + c0 * 16 + wv * 2) * 16)) * 64 + lane;
        short8 cw0 = w1p[w1L], cw1 = w1p[w1L + 1024];
#pragma unroll 2
        for (int ks = 0; ks < 16; ++ks) {
            short8 nw0, nw1;
            if (ks < 15) { nw0 = w1p[w1L + (ks + 1) * 64]; nw1 = w1p[w1L + (ks + 1) * 64 + 1024]; }
#pragma unroll
            for (int mt = 0; mt < 4; ++mt) {
                short8 a = *(const short8*)&Xf[(size_t)((mt * 16 + ks) * 64 + lane) * 8];
                aA[0][mt] = __builtin_amdgcn_mfma_f32_16x16x32_bf16(a, cw0, aA[0][mt], 0, 0, 0);
                aA[1][mt] = __builtin_amdgcn_mfma_f32_16x16x32_bf16(a, cw1, aA[1][mt], 0, 0, 0);
            }
            cw0 = nw0; cw1 = nw1;
        }
    }

    // ---- main: epilogue(c) then merged A(c+1)+B(c) (or drain B on last) ----
#pragma unroll 1
    for (int cc = 0; cc < 4; ++cc) {
        int c = c0 + cc;
        __syncthreads();   // previous B readers done with hs
        // write hs(c) = gelu(aA + b1)
#pragma unroll
        for (int nt = 0; nt < 2; ++nt) {
            int fg = (c * 16 + wv * 2 + nt) * 16 + n;
            float bb = b1[e * F_DIM + fg];
            int fl = (wv * 2 + nt) * 16 + n;
#pragma unroll
            for (int mt = 0; mt < 4; ++mt)
#pragma unroll
                for (int r = 0; r < 4; ++r) {
                    float h = aA[nt][mt][r] + bb;
                    h = 0.5f * h * (1.f + erff(h * 0.70710678118654752440f));
                    hs[mt * 16 + q * 4 + r][fl] = f2bf(h);
                }
        }
        __syncthreads();   // hs(c) ready

        size_t w2L = ((size_t)((e * 32 + wv * 4) * 64) + c * 8) * 64 + lane;
        short8 aH[4];

        if (cc < 3) {
            // merged: A(c+1) + B(c)
#pragma unroll
            for (int a = 0; a < 2; ++a)
#pragma unroll
                for (int b = 0; b < 4; ++b) aA[a][b] = (f32x4){0.f, 0.f, 0.f, 0.f};
            size_t w1L = ((size_t)((e * 128 + (c + 1) * 16 + wv * 2) * 16)) * 64 + lane;
            short8 cw0 = w1p[w1L], cw1 = w1p[w1L + 1024];
            short8 c2a = w2p[w2L], c2b = w2p[w2L + 4096];
#pragma unroll 2
            for (int it = 0; it < 16; ++it) {
                short8 nw0, nw1, n2a, n2b;
                int itn = it + 1;
                if (itn < 16) {
                    nw0 = w1p[w1L + itn * 64];
                    nw1 = w1p[w1L + itn * 64 + 1024];
                    size_t o2 = w2L + (size_t)(itn >> 1) * 64 + (size_t)(itn & 1) * 8192;
                    n2a = w2p[o2]; n2b = w2p[o2 + 4096];
                }
                if ((it & 1) == 0) {
                    int ks2 = it >> 1;
#pragma unroll
                    for (int mt = 0; mt < 4; ++mt)
                        aH[mt] = *(const short8*)&hs[mt * 16 + n][ks2 * 32 + q * 8];
                }
#pragma unroll
                for (int mt = 0; mt < 4; ++mt) {
                    short8 a = *(const short8*)&Xf[(size_t)((mt * 16 + it) * 64 + lane) * 8];
                    aA[0][mt] = __builtin_amdgcn_mfma_f32_16x16x32_bf16(a, cw0, aA[0][mt], 0, 0, 0);
                    aA[1][mt] = __builtin_amdgcn_mfma_f32_16x16x32_bf16(a, cw1, aA[1][mt], 0, 0, 0);
                }
                int nt0 = (it & 1) * 2;
#pragma unroll
                for (int mt = 0; mt < 4; ++mt)
                    aB[nt0][mt] = __builtin_amdgcn_mfma_f32_16x16x32_bf16(aH[mt], c2a, aB[nt0][mt], 0, 0, 0);
#pragma unroll
                for (int mt = 0; mt < 4; ++mt)
                    aB[nt0 + 1][mt] = __builtin_amdgcn_mfma_f32_16x16x32_bf16(aH[mt], c2b, aB[nt0 + 1][mt], 0, 0, 0);
                cw0 = nw0; cw1 = nw1; c2a = n2a; c2b = n2b;
            }
        } else {
            // drain: B(c3) only
            short8 c2a = w2p[w2L], c2b = w2p[w2L + 4096];
#pragma unroll 2
            for (int it = 0; it < 16; ++it) {
                short8 n2a, n2b;
                int itn = it + 1;
                if (itn < 16) {
                    size_t o2 = w2L + (size_t)(itn >> 1) * 64 + (size_t)(itn & 1) * 8192;
                    n2a = w2p[o2]; n2b = w2p[o2 + 4096];
                }
                if ((it & 1) == 0) {
                    int ks2 = it >> 1;
#pragma unroll
                    for (int mt = 0; mt < 4; ++mt)
                        aH[mt] = *(const short8*)&hs[mt * 16 + n][ks2 * 32 + q * 8];
                }
                int nt0 = (it & 1) * 2;
#pragma unroll
                for (int mt = 0; mt < 4; ++mt)
                    aB[nt0][mt] = __builtin_amdgcn_mfma_f32_16x16x32_bf16(aH[mt], c2a, aB[nt0][mt], 0, 0, 0);
#pragma unroll
                for (int mt = 0; mt < 4; ++mt)
                    aB[nt0 + 1][mt] = __builtin_amdgcn_mfma_f32_16x16x32_bf16(aH[mt], c2b, aB[nt0 + 1][mt], 0, 0, 0);
                c2a = n2a; c2b = n2b;
            }
        }
    }

    // ---- final epilogue: y += wgt * (out + b2 [half 0 only]) ---------------
#pragma unroll
    for (int nt = 0; nt < 4; ++nt) {
        int d = wv * 64 + nt * 16 + n;
        float bb = (half == 0) ? b2[e * D_DIM + d] : 0.f;
#pragma unroll
        for (int mt = 0; mt < 4; ++mt)
#pragma unroll
            for (int r = 0; r < 4; ++r) {
                int m = mt * 16 + q * 4 + r;
                float wg = swgt[m];
                if (wg != 0.f)
                    atomicAdd(y + (size_t)stok[m] * D_DIM + d, wg * (aB[nt][mt][r] + bb));
            }
    }
}

// ---------------------------------------------------------------------------
__global__ void moe_loss(const float* __restrict__ part, float* __restrict__ out) {
    __shared__ float pl[E_NUM];
    int tid = threadIdx.x;
    if (tid < E_NUM) pl[tid] = 0.f;
    __syncthreads();
    float s = 0.f;
    for (int i = tid; i < 256 * E_NUM; i += 256) s += part[i];   // i&7 constant per thread
    atomicAdd(&pl[tid & 7], s);
    __syncthreads();
    if (tid == 0) {
        float acc = 0.f;
        for (int e = 0; e < E_NUM; ++e) {
            float m = pl[e] / (float)T_TOKENS;
            acc += m * m;
        }
        out[0] = (float)E_NUM * acc;
    }
}

// ---------------------------------------------------------------------------
extern "C" void kernel_launch(void* const* d_in, const int* in_sizes, int n_in,
                              void* d_out, int out_size, void* d_ws, size_t ws_size,
                              hipStream_t stream) {
    const float* x  = (const float*)d_in[0];
    const float* gw = (const float*)d_in[1];
    const float* w1 = (const float*)d_in[2];
    const float* b1 = (const float*)d_in[3];
    const float* w2 = (const float*)d_in[4];
    const float* b2 = (const float*)d_in[5];
    float* out = (float*)d_out;

    char* ws = (char*)d_ws;
    int*   count     = (int*)(ws + WS_COUNT);
    float* part      = (float*)(ws + WS_PART);
    int*   tok_list  = (int*)(ws + WS_TOK);
    float* wgt_list  = (float*)(ws + WS_WGT);
    unsigned short* w1b = (unsigned short*)(ws + WS_W1B);
    unsigned short* w2b = (unsigned short*)(ws + WS_W2B);

    hipMemsetAsync(d_out, 0, (size_t)out_size * sizeof(float), stream);
    moe_init<<<1, 64, 0, stream>>>(count);
    moe_convert<<<8192, 256, 0, stream>>>(w1, w2, w1b, w2b);
    moe_router<<<T_TOKENS / 32, 256, 0, stream>>>(x, gw, count, tok_list, wgt_list, part);
    moe_ffn<<<E_NUM * 2 * 128, 512, 0, stream>>>(x, w1b, b1, w2b, b2, count, tok_list, wgt_list, out);
    moe_loss<<<1, 256, 0, stream>>>(part, out + (size_t)T_TOKENS * D_DIM);
}